// Round 19
// baseline (58.372 us; speedup 1.0000x reference)
//
#include <hip/hip_runtime.h>

#define NTOK 4096
#define DIM 32
#define NBH 32              // B*H

// ---------- MFMA phase1 layout ----------
#define BHF1 18496          // 576 rows * 32 f + 64 sums (slot-0 float units)
#define SLOT1 591872        // NBH * BHF1
#define SUMOFF1 18432       // 576*32
#define KCH1 32             // phase1 token chunks (128 tok each)
#define TSF2 132            // skT token stride (fp32, 128 tok + pad)
#define TSH2 136            // svT token stride (fp16, 128 tok + pad)

// ws layout (float offsets): [0, SLOT1) slot-0 fp32 (final sums);
// [SLOT1, 17*SLOT1) = 32 partial slots of SLOT1 u16 (f16) each;
// then partial sums fp32; then bpk (u32).
#define PRT_OFF SLOT1
#define PSUM_OFF (17 * SLOT1)
#define PSUM_SZ (KCH1 * NBH * 64)          // 65536 floats
#define BPK_OFF (PSUM_OFF + PSUM_SZ)

#define KCH 18              // phase2 K-chunks (K = 576)
#define PK_U32 (NBH * KCH * 1024)   // 589,824 packed frag u32 (hi+lo planes)
#define PK_HALF (PK_U32 / 2)        // 294,912 pack threads
#define P2TOK 64            // 1 wave per block

// ---------- OLD (fallback) layout ----------
#define NPAIR2 528
#define NROWS 560
#define BHF (NROWS * 32 + 64)
#define SLOT (NBH * BHF)
#define TILE 64
#define LSTR 36
#define P1T 320

typedef __attribute__((ext_vector_type(8))) short bf16x8;
typedef __attribute__((ext_vector_type(8))) _Float16 f16x8;
typedef __attribute__((ext_vector_type(4))) _Float16 f16x4;
typedef __attribute__((ext_vector_type(4))) float f32x4;
typedef __attribute__((ext_vector_type(4))) unsigned u32x4;
typedef __attribute__((ext_vector_type(2))) unsigned u32x2;

__device__ __forceinline__ int tri_start(int d) { return (d * (65 - d)) >> 1; }

__device__ __forceinline__ int tri_decode_d(int p) {
    int d = (int)((65.0f - sqrtf((float)(4225 - 8 * p))) * 0.5f);
    if (d < 0) d = 0;
    if (d > 31) d = 31;
    while (d < 31 && tri_start(d + 1) <= p) ++d;
    while (d > 0 && tri_start(d) > p) --d;
    return d;
}

__device__ __forceinline__ void row_operands(int row, int& ia, int& ib) {
    if (row < NPAIR2) {
        const int d = tri_decode_d(row);
        ia = d; ib = d + (row - tri_start(d));
    } else if (row < NROWS) {
        ia = row - NPAIR2; ib = 32;
    } else {
        ia = 34; ib = 34;
    }
}

__device__ __forceinline__ unsigned short h16(float x) {
    return __builtin_bit_cast(unsigned short, (_Float16)x);
}
__device__ __forceinline__ float h2f(unsigned short u) {
    return (float)__builtin_bit_cast(_Float16, u);
}

// packed RTZ f32x2 -> f16x2 (as u32), plus the hi values back as floats for residuals
__device__ __forceinline__ unsigned pkrtz_u32(float a, float b, float& ha, float& hb) {
    const auto h = __builtin_amdgcn_cvt_pkrtz(a, b);   // __fp16 ext_vector(2)
    ha = (float)h[0];
    hb = (float)h[1];
    return __builtin_bit_cast(unsigned, h);
}
__device__ __forceinline__ unsigned pkrtz_u32(float a, float b) {
    return __builtin_bit_cast(unsigned, __builtin_amdgcn_cvt_pkrtz(a, b));
}

// fp32[8] -> f16 hi/lo fragments via packed converter (hi rounding compensated by lo)
__device__ __forceinline__ void split8(const float* p, f16x8& hi, f16x8& lo) {
    unsigned hw[4], lw[4];
#pragma unroll
    for (int j = 0; j < 4; ++j) {
        float h0, h1;
        hw[j] = pkrtz_u32(p[2 * j], p[2 * j + 1], h0, h1);
        lw[j] = pkrtz_u32(p[2 * j] - h0, p[2 * j + 1] - h1);
    }
    hi = __builtin_bit_cast(f16x8, (u32x4){hw[0], hw[1], hw[2], hw[3]});
    lo = __builtin_bit_cast(f16x8, (u32x4){lw[0], lw[1], lw[2], lw[3]});
}

#define MF(A, B, C) __builtin_amdgcn_mfma_f32_16x16x32_f16((A), (B), (C), 0, 0, 0)

// =================== Phase 1 (MFMA, fp32-exact A-products) ===================
// 128 tokens per chunk (KCH1=32) -> 1024 blocks = 4 blocks/CU for latency hiding.
// W row R = o*32+d (o=0..16, pair (d,(d+o)&31)); R = 544+d: kv1.
// Partials stored f16 (2B); partial sums fp32 in PSUM region.
__global__ __launch_bounds__(256) void phase1m_kernel(const float* __restrict__ qkv,
                                                      float* __restrict__ ws) {
    const int chunk = blockIdx.x;
    const int bh = blockIdx.y;
    const int t = threadIdx.x;
    const int w = t >> 6, l = t & 63, g = l >> 4, c16 = l & 15;

    __shared__ float skT[32 * TSF2];       // 16.5 KB
    __shared__ _Float16 svhiT[32 * TSH2];  // 8.5 KB
    __shared__ _Float16 svloT[32 * TSH2];  // 8.5 KB

    const float4* kg4 = (const float4*)(qkv + (size_t)(NBH + bh) * (NTOK * DIM)) + (size_t)chunk * 128 * 8;
    const float4* vg4 = (const float4*)(qkv + (size_t)(2 * NBH + bh) * (NTOK * DIM)) + (size_t)chunk * 128 * 8;

    f32x4 acc[4][2][2];
    f32x4 accS[2][2];
#pragma unroll
    for (int i = 0; i < 4; ++i)
#pragma unroll
        for (int m = 0; m < 2; ++m)
#pragma unroll
            for (int fh = 0; fh < 2; ++fh) acc[i][m][fh] = (f32x4){0.f, 0.f, 0.f, 0.f};
#pragma unroll
    for (int m = 0; m < 2; ++m)
#pragma unroll
        for (int fh = 0; fh < 2; ++fh) accS[m][fh] = (f32x4){0.f, 0.f, 0.f, 0.f};

    const f16x8 ones = {(_Float16)1.f, (_Float16)1.f, (_Float16)1.f, (_Float16)1.f,
                        (_Float16)1.f, (_Float16)1.f, (_Float16)1.f, (_Float16)1.f};

    const int fq = t >> 5;     // 0..7 feature-quad
    const int tq = t & 31;     // 0..31 token-quad

    {   // ---- stage 128 tokens: 4x4 register-tile transpose ----
        float4 kf[4], vf[4];
#pragma unroll
        for (int c = 0; c < 4; ++c) {
            kf[c] = kg4[(size_t)(tq * 4 + c) * 8 + fq];
            vf[c] = vg4[(size_t)(tq * 4 + c) * 8 + fq];
        }
        const float kr[4][4] = {{kf[0].x, kf[1].x, kf[2].x, kf[3].x},
                                {kf[0].y, kf[1].y, kf[2].y, kf[3].y},
                                {kf[0].z, kf[1].z, kf[2].z, kf[3].z},
                                {kf[0].w, kf[1].w, kf[2].w, kf[3].w}};
        const float vr[4][4] = {{vf[0].x, vf[1].x, vf[2].x, vf[3].x},
                                {vf[0].y, vf[1].y, vf[2].y, vf[3].y},
                                {vf[0].z, vf[1].z, vf[2].z, vf[3].z},
                                {vf[0].w, vf[1].w, vf[2].w, vf[3].w}};
#pragma unroll
        for (int r = 0; r < 4; ++r) {
            *(float4*)(skT + (fq * 4 + r) * TSF2 + tq * 4) =
                (float4){kr[r][0], kr[r][1], kr[r][2], kr[r][3]};
            float h0, h1, h2, h3;
            const unsigned hw0 = pkrtz_u32(vr[r][0], vr[r][1], h0, h1);
            const unsigned hw1 = pkrtz_u32(vr[r][2], vr[r][3], h2, h3);
            const unsigned lw0 = pkrtz_u32(vr[r][0] - h0, vr[r][1] - h1);
            const unsigned lw1 = pkrtz_u32(vr[r][2] - h2, vr[r][3] - h3);
            *(u32x2*)(svhiT + (fq * 4 + r) * TSH2 + tq * 4) = (u32x2){hw0, hw1};
            *(u32x2*)(svloT + (fq * 4 + r) * TSH2 + tq * 4) = (u32x2){lw0, lw1};
        }
    }
    __syncthreads();

#pragma unroll 1
    for (int it = 0; it < 4; ++it) {
        const int sl = it * 32 + 8 * g;
        float a0[8], a1[8];
        *(float4*)&a0[0] = *(const float4*)(skT + c16 * TSF2 + sl);
        *(float4*)&a0[4] = *(const float4*)(skT + c16 * TSF2 + sl + 4);
        *(float4*)&a1[0] = *(const float4*)(skT + (16 + c16) * TSF2 + sl);
        *(float4*)&a1[4] = *(const float4*)(skT + (16 + c16) * TSF2 + sl + 4);
        const f16x8 Bh0 = *(const f16x8*)(svhiT + c16 * TSH2 + sl);
        const f16x8 Bh1 = *(const f16x8*)(svhiT + (16 + c16) * TSH2 + sl);
        const f16x8 Bl0 = *(const f16x8*)(svloT + c16 * TSH2 + sl);
        const f16x8 Bl1 = *(const f16x8*)(svloT + (16 + c16) * TSH2 + sl);

#pragma unroll
        for (int i = 0; i < 4; ++i) {
            const int o = w + 4 * i;
            const int r0 = ((c16 + o) & 31) * TSF2;
            const int r1 = ((16 + c16 + o) & 31) * TSF2;
            float e0[8], e1[8], p0[8], p1[8];
            *(float4*)&e0[0] = *(const float4*)(skT + r0 + sl);
            *(float4*)&e0[4] = *(const float4*)(skT + r0 + sl + 4);
            *(float4*)&e1[0] = *(const float4*)(skT + r1 + sl);
            *(float4*)&e1[4] = *(const float4*)(skT + r1 + sl + 4);
#pragma unroll
            for (int j = 0; j < 8; ++j) { p0[j] = a0[j] * e0[j]; p1[j] = a1[j] * e1[j]; }
            f16x8 A0h, A0l, A1h, A1l;
            split8(p0, A0h, A0l);
            split8(p1, A1h, A1l);
            acc[i][0][0] = MF(A0h, Bh0, acc[i][0][0]);
            acc[i][0][0] = MF(A0l, Bh0, acc[i][0][0]);
            acc[i][0][0] = MF(A0h, Bl0, acc[i][0][0]);
            acc[i][0][1] = MF(A0h, Bh1, acc[i][0][1]);
            acc[i][0][1] = MF(A0l, Bh1, acc[i][0][1]);
            acc[i][0][1] = MF(A0h, Bl1, acc[i][0][1]);
            acc[i][1][0] = MF(A1h, Bh0, acc[i][1][0]);
            acc[i][1][0] = MF(A1l, Bh0, acc[i][1][0]);
            acc[i][1][0] = MF(A1h, Bl0, acc[i][1][0]);
            acc[i][1][1] = MF(A1h, Bh1, acc[i][1][1]);
            acc[i][1][1] = MF(A1l, Bh1, acc[i][1][1]);
            acc[i][1][1] = MF(A1h, Bl1, acc[i][1][1]);
        }

        if (w == 0) {            // o=16 (duplicate-symmetric pair rows)
            float p[8];
#pragma unroll
            for (int j = 0; j < 8; ++j) p[j] = a0[j] * a1[j];
            f16x8 Ah, Al;
            split8(p, Ah, Al);
            accS[0][0] = MF(Ah, Bh0, accS[0][0]);
            accS[0][0] = MF(Al, Bh0, accS[0][0]);
            accS[0][0] = MF(Ah, Bl0, accS[0][0]);
            accS[0][1] = MF(Ah, Bh1, accS[0][1]);
            accS[0][1] = MF(Al, Bh1, accS[0][1]);
            accS[0][1] = MF(Ah, Bl1, accS[0][1]);
        } else if (w == 1) {     // kv1: A = k (split)
            f16x8 K0h, K0l, K1h, K1l;
            split8(a0, K0h, K0l);
            split8(a1, K1h, K1l);
            accS[0][0] = MF(K0h, Bh0, accS[0][0]);
            accS[0][0] = MF(K0l, Bh0, accS[0][0]);
            accS[0][0] = MF(K0h, Bl0, accS[0][0]);
            accS[0][1] = MF(K0h, Bh1, accS[0][1]);
            accS[0][1] = MF(K0l, Bh1, accS[0][1]);
            accS[0][1] = MF(K0h, Bl1, accS[0][1]);
            accS[1][0] = MF(K1h, Bh0, accS[1][0]);
            accS[1][0] = MF(K1l, Bh0, accS[1][0]);
            accS[1][0] = MF(K1h, Bl0, accS[1][0]);
            accS[1][1] = MF(K1h, Bh1, accS[1][1]);
            accS[1][1] = MF(K1l, Bh1, accS[1][1]);
            accS[1][1] = MF(K1h, Bl1, accS[1][1]);
        } else if (w == 2) {     // ksum: A = ones, B = k (split)
            f16x8 K0h, K0l, K1h, K1l;
            split8(a0, K0h, K0l);
            split8(a1, K1h, K1l);
            accS[0][0] = MF(ones, K0h, accS[0][0]);
            accS[0][0] = MF(ones, K0l, accS[0][0]);
            accS[1][0] = MF(ones, K1h, accS[1][0]);
            accS[1][0] = MF(ones, K1l, accS[1][0]);
        } else {                 // vsum: A = ones, B = v hi/lo
            accS[0][0] = MF(ones, Bh0, accS[0][0]);
            accS[0][0] = MF(ones, Bl0, accS[0][0]);
            accS[0][1] = MF(ones, Bh1, accS[0][1]);
            accS[0][1] = MF(ones, Bl1, accS[0][1]);
        }
    }

    // ---- store partials (f16, 2B) to slot `chunk`; sums fp32 to PSUM ----
    unsigned short* pb = (unsigned short*)(ws + PRT_OFF) + (size_t)SLOT1 * chunk + (size_t)bh * BHF1;
#pragma unroll
    for (int i = 0; i < 4; ++i) {
        const int o = w + 4 * i;
#pragma unroll
        for (int m = 0; m < 2; ++m)
#pragma unroll
            for (int fh = 0; fh < 2; ++fh)
#pragma unroll
                for (int r = 0; r < 4; ++r) {
                    const int R = o * 32 + 16 * m + 4 * g + r;
                    pb[(size_t)R * 32 + fh * 16 + c16] = h16(acc[i][m][fh][r]);
                }
    }
    if (w == 0) {
#pragma unroll
        for (int fh = 0; fh < 2; ++fh)
#pragma unroll
            for (int r = 0; r < 4; ++r) {
                const int R = 512 + 4 * g + r;
                const unsigned short hv = h16(accS[0][fh][r]);
                pb[(size_t)R * 32 + fh * 16 + c16] = hv;
                pb[(size_t)(R + 16) * 32 + fh * 16 + c16] = hv;
            }
    } else if (w == 1) {
#pragma unroll
        for (int m = 0; m < 2; ++m)
#pragma unroll
            for (int fh = 0; fh < 2; ++fh)
#pragma unroll
                for (int r = 0; r < 4; ++r) {
                    const int R = 544 + 16 * m + 4 * g + r;
                    pb[(size_t)R * 32 + fh * 16 + c16] = h16(accS[m][fh][r]);
                }
    } else if (w == 2) {
        if (g == 0) {
            float* ps = ws + PSUM_OFF + (size_t)chunk * (NBH * 64) + bh * 64;
            ps[c16] = accS[0][0][0];
            ps[16 + c16] = accS[1][0][0];
        }
    } else {
        if (g == 0) {
            float* ps = ws + PSUM_OFF + (size_t)chunk * (NBH * 64) + bh * 64;
            ps[32 + c16] = accS[0][0][0];
            ps[48 + c16] = accS[0][1][0];
        }
    }
}

// ============ reduce (32 f16 slots) + prep (f16 hi/lo B-frag pack) + sums ============
__global__ __launch_bounds__(256) void reduceprep_kernel(const float* __restrict__ ws,
                                                         float* __restrict__ wsw,
                                                         unsigned* __restrict__ bpk) {
    const int tid = blockIdx.x * 256 + threadIdx.x;
    if (tid < PK_HALF) {
        const int r = tid & 3;
        const int l = (tid >> 2) & 63;
        const int fh = (tid >> 8) & 1;
        const int kcbh = tid >> 9;
        const int kc = kcbh % KCH;
        const int bh = kcbh / KCH;
        const int f = fh * 16 + (l & 15);
        const int k0 = kc * 32 + ((l >> 4) << 3) + 2 * r;
        const float scale = (kc == 0 || kc == 16) ? 0.5f : 1.0f;
        float va = 0.f, vb = 0.f;
        const unsigned short* up = (const unsigned short*)(ws + PRT_OFF) +
                                   (size_t)bh * BHF1 + (size_t)k0 * 32 + f;
#pragma unroll
        for (int c = 0; c < KCH1; ++c) {
            va += h2f(up[(size_t)SLOT1 * c]);
            vb += h2f(up[(size_t)SLOT1 * c + 32]);
        }
        va *= scale; vb *= scale;
        float ha, hb;
        const unsigned hw = pkrtz_u32(va, vb, ha, hb);
        const unsigned lw = pkrtz_u32(va - ha, vb - hb);
        const int widx = ((bh * KCH + kc) * 2 + fh) * 512 + l * 4 + r;
        bpk[widx] = hw;
        bpk[widx + 256] = lw;
    } else {
        const int tid2 = tid - PK_HALF;
        if (tid2 < NBH * 64) {
            const int bh = tid2 >> 6;
            const int j = tid2 & 63;
            float s = 0.f;
            const float* src = ws + PSUM_OFF + bh * 64 + j;
#pragma unroll
            for (int c = 0; c < KCH1; ++c) s += src[(size_t)c * (NBH * 64)];
            wsw[(size_t)bh * BHF1 + SUMOFF1 + j] = s;
        }
    }
}

// ====== phase 2 (r17 champion): y = Phi(A) * W(B) via f16 MFMA + pkrtz pack ======
#define EMIT_MFMA(PHIEXPR, KCEXPR) do { \
    unsigned hh[16]; \
    _Pragma("unroll") \
    for (int kp = 0; kp < 16; ++kp) { \
        const int j0 = 2 * kp, j1 = 2 * kp + 1; \
        const float p0 = (PHIEXPR(j0)); \
        const float p1 = (PHIEXPR(j1)); \
        hh[kp] = pkrtz_u32(p0, p1); \
    } \
    _Pragma("unroll") \
    for (int c4 = 0; c4 < 4; ++c4) { \
        u32x4 vh = {hh[4 * c4], hh[4 * c4 + 1], hh[4 * c4 + 2], hh[4 * c4 + 3]}; \
        *(u32x4*)&sph[t * 20 + c4 * 4] = vh; \
    } \
    const unsigned* bc = bbase + (size_t)(KCEXPR) * 1024; \
    const f16x8 Bh0 = __builtin_bit_cast(f16x8, *(const u32x4*)(bc + 0   + t * 4)); \
    const f16x8 Bl0 = __builtin_bit_cast(f16x8, *(const u32x4*)(bc + 256 + t * 4)); \
    const f16x8 Bh1 = __builtin_bit_cast(f16x8, *(const u32x4*)(bc + 512 + t * 4)); \
    const f16x8 Bl1 = __builtin_bit_cast(f16x8, *(const u32x4*)(bc + 768 + t * 4)); \
    _Pragma("unroll") \
    for (int T = 0; T < 4; ++T) { \
        const int ro = (T * 16 + arow) * 20 + acol; \
        const f16x8 Ah = __builtin_bit_cast(f16x8, *(const u32x4*)&sph[ro]); \
        acc[T][0] = MF(Ah, Bh0, acc[T][0]); \
        acc[T][0] = MF(Ah, Bl0, acc[T][0]); \
        acc[T][1] = MF(Ah, Bh1, acc[T][1]); \
        acc[T][1] = MF(Ah, Bl1, acc[T][1]); \
    } \
} while (0)

__global__ __launch_bounds__(P2TOK) void phase2m_kernel(const float* __restrict__ qkv,
                                                        const float* __restrict__ ws,
                                                        const unsigned* __restrict__ bpk,
                                                        float* __restrict__ out) {
    const int bh = blockIdx.y;
    const int tok0 = blockIdx.x * P2TOK;
    const int t = threadIdx.x;          // 0..63 == lane
    const int arow = t & 15;
    const int acol = (t >> 4) << 2;

    __shared__ unsigned sph[P2TOK * 20];
    __shared__ float sinv[P2TOK];

    float q[32];
    {
        const float4* q4 = (const float4*)(qkv + ((size_t)bh * NTOK + tok0 + t) * DIM);
#pragma unroll
        for (int i = 0; i < 8; ++i) {
            const float4 v = q4[i];
            q[4 * i + 0] = v.x; q[4 * i + 1] = v.y; q[4 * i + 2] = v.z; q[4 * i + 3] = v.w;
        }
    }
    {
        const float* ks = ws + (size_t)bh * BHF1 + SUMOFF1;
        float qk = 0.f;
#pragma unroll
        for (int d = 0; d < 32; ++d) qk += q[d] * ks[d];
        sinv[t] = 1.0f / (0.5f * qk * qk + qk + 1.0f);
    }

    f32x4 acc[4][2];
#pragma unroll
    for (int T = 0; T < 4; ++T)
#pragma unroll
        for (int fh = 0; fh < 2; ++fh) acc[T][fh] = (f32x4){0.f, 0.f, 0.f, 0.f};

    const unsigned* bbase = bpk + (size_t)bh * (KCH * 1024);

    float qr[32];
#pragma unroll
    for (int j = 0; j < 32; ++j) qr[j] = q[j];

#pragma unroll 1
    for (int kc4 = 0; kc4 < 16; kc4 += 4) {
#define PHI_S0(J) (q[(J)] * qr[(J)])
#define PHI_S1(J) (q[(J)] * qr[((J) + 1) & 31])
#define PHI_S2(J) (q[(J)] * qr[((J) + 2) & 31])
#define PHI_S3(J) (q[(J)] * qr[((J) + 3) & 31])
        EMIT_MFMA(PHI_S0, kc4 + 0);
        EMIT_MFMA(PHI_S1, kc4 + 1);
        EMIT_MFMA(PHI_S2, kc4 + 2);
        EMIT_MFMA(PHI_S3, kc4 + 3);
#undef PHI_S0
#undef PHI_S1
#undef PHI_S2
#undef PHI_S3
        // rotate qr by 4
        const float t0 = qr[0], t1 = qr[1], t2 = qr[2], t3 = qr[3];
#pragma unroll
        for (int j = 0; j < 28; ++j) qr[j] = qr[j + 4];
        qr[28] = t0; qr[29] = t1; qr[30] = t2; qr[31] = t3;
    }
    // kc = 16: qr is now q rotated by 16
    {
#define PHI_16(J) (q[(J)] * qr[(J)])
        EMIT_MFMA(PHI_16, 16);
#undef PHI_16
    }
    // kc = 17: kv1, phi = q
    {
#define PHI_Q(J) (q[(J)])
        EMIT_MFMA(PHI_Q, 17);
#undef PHI_Q
    }

    const float* vs = ws + (size_t)bh * BHF1 + SUMOFF1 + 32;
    const float vs0 = vs[t & 15];
    const float vs1 = vs[16 + (t & 15)];
#pragma unroll
    for (int T = 0; T < 4; ++T) {
#pragma unroll
        for (int r = 0; r < 4; ++r) {
            const int row = T * 16 + ((t >> 4) << 2) + r;
            const float iv = sinv[row];
            float* op = out + ((size_t)bh * NTOK + tok0 + row) * DIM + (t & 15);
            op[0]  = (acc[T][0][r] + vs0) * iv;
            op[16] = (acc[T][1][r] + vs1) * iv;
        }
    }
}

// =================== OLD fallback path (proven) ===================
__global__ __launch_bounds__(P1T) void phase1_kernel(const float* __restrict__ qkv,
                                                     float* __restrict__ ws, int direct) {
    const int chunk = blockIdx.x;
    const int bh = blockIdx.y;
    const int CHt = NTOK / gridDim.x;
    const int t = threadIdx.x;
    const float* kptr = qkv + (size_t)(NBH + bh) * (NTOK * DIM);
    const float* vptr = qkv + (size_t)(2 * NBH + bh) * (NTOK * DIM);
    float* base = ws + (direct ? (size_t)0 : (size_t)SLOT * (1 + chunk)) + (size_t)bh * BHF;

    __shared__ __align__(16) float sk[TILE][LSTR];
    __shared__ __align__(16) float sv[TILE][LSTR];

    int ia0, ib0, ia1, ib1;
    row_operands(t, ia0, ib0);
    row_operands(t + P1T, ia1, ib1);
    const float* a0 = &sk[0][ia0];
    const float* b0 = &sk[0][ib0];
    const float* a1 = &sk[0][ia1];
    const float* b1 = &sk[0][ib1];
    const float* sums = (t >= 288) ? &sv[0][t - 288] : ((t >= 256) ? &sk[0][t - 256] : &sk[0][0]);

    float acc0[32], acc1[32];
#pragma unroll
    for (int f = 0; f < 32; ++f) { acc0[f] = 0.f; acc1[f] = 0.f; }
    float accs = 0.f;

    if (t < 64) sk[t][32] = 1.0f;
    else if (t < 128) sk[t - 64][34] = 0.0f;

    const int n0 = chunk * CHt;
    for (int nt = 0; nt < CHt; nt += TILE) {
        __syncthreads();
        if (t < 256) {
            const float4* kg4 = (const float4*)(kptr + (size_t)(n0 + nt) * DIM);
            const float4* vg4 = (const float4*)(vptr + (size_t)(n0 + nt) * DIM);
            const int i0 = t, i1 = t + 256;
            *(float4*)&sk[i0 >> 3][(i0 & 7) << 2] = kg4[i0];
            *(float4*)&sk[i1 >> 3][(i1 & 7) << 2] = kg4[i1];
            *(float4*)&sv[i0 >> 3][(i0 & 7) << 2] = vg4[i0];
            *(float4*)&sv[i1 >> 3][(i1 & 7) << 2] = vg4[i1];
        }
        __syncthreads();
#pragma unroll 2
        for (int nn = 0; nn < TILE; ++nn) {
            const float s0 = a0[nn * LSTR] * b0[nn * LSTR];
            const float s1 = a1[nn * LSTR] * b1[nn * LSTR];
            const float* vrow = vptr + (size_t)(n0 + nt + nn) * DIM;
            float4 w[8];
#pragma unroll
            for (int j = 0; j < 8; ++j) w[j] = ((const float4*)vrow)[j];
#pragma unroll
            for (int j = 0; j < 8; ++j) {
                acc0[4 * j + 0] += s0 * w[j].x; acc0[4 * j + 1] += s0 * w[j].y;
                acc0[4 * j + 2] += s0 * w[j].z; acc0[4 * j + 3] += s0 * w[j].w;
                acc1[4 * j + 0] += s1 * w[j].x; acc1[4 * j + 1] += s1 * w[j].y;
                acc1[4 * j + 2] += s1 * w[j].z; acc1[4 * j + 3] += s1 * w[j].w;
            }
            if (t >= 256) accs += sums[nn * LSTR];
        }
    }

    {
        float* dst = base + (size_t)t * 32;
#pragma unroll
        for (int j = 0; j < 8; ++j) {
            float4 v; v.x = acc0[4 * j]; v.y = acc0[4 * j + 1];
            v.z = acc0[4 * j + 2]; v.w = acc0[4 * j + 3];
            ((float4*)dst)[j] = v;
        }
    }
    if (t < 240) {
        float* dst = base + (size_t)(t + P1T) * 32;
#pragma unroll
        for (int j = 0; j < 8; ++j) {
            float4 v; v.x = acc1[4 * j]; v.y = acc1[4 * j + 1];
            v.z = acc1[4 * j + 2]; v.w = acc1[4 * j + 3];
            ((float4*)dst)[j] = v;
        }
    }
    if (t >= 256) base[NROWS * 32 + (t - 256)] = accs;
}

__global__ __launch_bounds__(256) void phase2_kernel(const float* __restrict__ qkv,
                                                     const float* __restrict__ ws,
                                                     float* __restrict__ out) {
    const int bh = blockIdx.y;
    const int f0 = blockIdx.z << 4;
    const int t = threadIdx.x;
    const int tok0 = blockIdx.x * 256;
    const float* qptr = qkv + (size_t)bh * (NTOK * DIM) + (size_t)tok0 * DIM;
    const float* base = ws + (size_t)bh * BHF;
    const float* ksum = base + NROWS * 32;
    const float* vsum = ksum + 32;

    __shared__ float qT[32][256];
    {
        const float4* q4 = (const float4*)qptr + (size_t)t * 8;
#pragma unroll
        for (int i = 0; i < 8; ++i) {
            const float4 v = q4[i];
            qT[4 * i + 0][t] = v.x; qT[4 * i + 1][t] = v.y;
            qT[4 * i + 2][t] = v.z; qT[4 * i + 3][t] = v.w;
        }
    }
    __syncthreads();

    float y[16];
#pragma unroll
    for (int j = 0; j < 4; ++j) {
        const float4 v = *(const float4*)(vsum + f0 + 4 * j);
        y[4 * j + 0] = v.x; y[4 * j + 1] = v.y; y[4 * j + 2] = v.z; y[4 * j + 3] = v.w;
    }
    float qk = 0.f;
    const float* rowp = base + f0;
#pragma unroll 1
    for (int d = 0; d < 32; ++d) {
        const float qd = qT[d][t];
        qk += qd * ksum[d];
        {
            const float s = 0.5f * qd * qd;
            const float4* r = (const float4*)rowp;
#pragma unroll
            for (int j = 0; j < 4; ++j) {
                const float4 w = r[j];
                y[4 * j + 0] += s * w.x; y[4 * j + 1] += s * w.y;
                y[4 * j + 2] += s * w.z; y[4 * j + 3] += s * w.w;
            }
            rowp += 32;
        }
#pragma unroll 4
        for (int e = d + 1; e < 32; ++e) {
            const float s = qd * qT[e][t];
            const float4* r = (const float4*)rowp;
#pragma unroll
            for (int j = 0; j < 4; ++j) {
                const float4 w = r[j];
                y[4 * j + 0] += s * w.x; y[4 * j + 1] += s * w.y;
                y[4 * j + 2] += s * w.z; y[4 * j + 3] += s * w.w;
            }
            rowp += 32;
        }
    }
#pragma unroll 4
    for (int d = 0; d < 32; ++d) {
        const float qd = qT[d][t];
        const float4* r = (const float4*)rowp;
#pragma unroll
        for (int j = 0; j < 4; ++j) {
            const float4 w = r[j];
            y[4 * j + 0] += qd * w.x; y[4 * j + 1] += qd * w.y;
            y[4 * j + 2] += qd * w.z; y[4 * j + 3] += qd * w.w;
        }
        rowp += 32;
    }
    const float inv = 1.0f / (0.5f * qk * qk + qk + 1.0f);
    float4* o4 = (float4*)(out + (size_t)bh * (NTOK * DIM) + (size_t)(tok0 + t) * DIM + f0);
#pragma unroll
    for (int j = 0; j < 4; ++j) {
        float4 v;
        v.x = y[4 * j + 0] * inv; v.y = y[4 * j + 1] * inv;
        v.z = y[4 * j + 2] * inv; v.w = y[4 * j + 3] * inv;
        o4[j] = v;
    }
}

extern "C" void kernel_launch(void* const* d_in, const int* in_sizes, int n_in,
                              void* d_out, int out_size, void* d_ws, size_t ws_size,
                              hipStream_t stream) {
    const float* qkv = (const float*)d_in[0];
    float* out = (float*)d_out;
    float* ws = (float*)d_ws;

    const size_t need = ((size_t)BPK_OFF + PK_U32) * 4;
    if (ws_size >= need) {
        unsigned* bpk = (unsigned*)(ws + BPK_OFF);
        phase1m_kernel<<<dim3(KCH1, NBH), dim3(256), 0, stream>>>(qkv, ws);
        reduceprep_kernel<<<dim3((PK_HALF + NBH * 64 + 255) / 256), dim3(256), 0, stream>>>(ws, ws, bpk);
        phase2m_kernel<<<dim3(NTOK / P2TOK, NBH), dim3(P2TOK), 0, stream>>>(qkv, ws, bpk, out);
    } else {
        phase1_kernel<<<dim3(1, NBH), dim3(P1T), 0, stream>>>(qkv, ws, 1);
        phase2_kernel<<<dim3(NTOK / 256, NBH, 2), dim3(256), 0, stream>>>(qkv, ws, out);
    }
}

// Round 20
// 50.750 us; speedup vs baseline: 1.1502x; 1.1502x over previous
//
#include <hip/hip_runtime.h>

#define NTOK 4096
#define DIM 32
#define NBH 32              // B*H

// ---------- MFMA phase1 layout ----------
#define BHF1 18496          // 576 rows * 32 f + 64 sums (slot-0 float units)
#define SLOT1 591872        // NBH * BHF1
#define SUMOFF1 18432       // 576*32
#define KCH1 16             // phase1 token chunks (256 tok each)
#define TSF2 132            // skT token stride (fp32, 128 tok + pad)
#define TSH2 136            // svT token stride (fp16, 128 tok + pad)

// ws layout (float offsets): [0, SLOT1) slot-0 fp32 (final sums);
// [SLOT1, 9*SLOT1) = 16 partial slots of SLOT1 u16 (f16) each;
// [9*SLOT1, +PSUM_SZ) partial sums fp32; then bpk (u32).
#define PRT_OFF SLOT1
#define PSUM_OFF (9 * SLOT1)
#define PSUM_SZ (KCH1 * NBH * 64)          // 32768 floats
#define BPK_OFF (PSUM_OFF + PSUM_SZ)

#define KCH 18              // phase2 K-chunks (K = 576)
#define PK_U32 (NBH * KCH * 1024)   // 589,824 packed frag u32 (hi+lo planes)
#define PK_HALF (PK_U32 / 2)        // 294,912 pack threads
#define P2TOK 64            // 1 wave per block

// ---------- OLD (fallback) layout ----------
#define NPAIR2 528
#define NROWS 560
#define BHF (NROWS * 32 + 64)
#define SLOT (NBH * BHF)
#define TILE 64
#define LSTR 36
#define P1T 320

typedef __attribute__((ext_vector_type(8))) short bf16x8;
typedef __attribute__((ext_vector_type(8))) _Float16 f16x8;
typedef __attribute__((ext_vector_type(4))) _Float16 f16x4;
typedef __attribute__((ext_vector_type(4))) float f32x4;
typedef __attribute__((ext_vector_type(4))) unsigned u32x4;
typedef __attribute__((ext_vector_type(2))) unsigned u32x2;

__device__ __forceinline__ int tri_start(int d) { return (d * (65 - d)) >> 1; }

__device__ __forceinline__ int tri_decode_d(int p) {
    int d = (int)((65.0f - sqrtf((float)(4225 - 8 * p))) * 0.5f);
    if (d < 0) d = 0;
    if (d > 31) d = 31;
    while (d < 31 && tri_start(d + 1) <= p) ++d;
    while (d > 0 && tri_start(d) > p) --d;
    return d;
}

__device__ __forceinline__ void row_operands(int row, int& ia, int& ib) {
    if (row < NPAIR2) {
        const int d = tri_decode_d(row);
        ia = d; ib = d + (row - tri_start(d));
    } else if (row < NROWS) {
        ia = row - NPAIR2; ib = 32;
    } else {
        ia = 34; ib = 34;
    }
}

__device__ __forceinline__ unsigned short h16(float x) {
    return __builtin_bit_cast(unsigned short, (_Float16)x);
}
__device__ __forceinline__ float h2f(unsigned short u) {
    return (float)__builtin_bit_cast(_Float16, u);
}

// packed RTZ f32x2 -> f16x2 (as u32), plus the hi values back as floats for residuals
__device__ __forceinline__ unsigned pkrtz_u32(float a, float b, float& ha, float& hb) {
    const auto h = __builtin_amdgcn_cvt_pkrtz(a, b);   // __fp16 ext_vector(2)
    ha = (float)h[0];
    hb = (float)h[1];
    return __builtin_bit_cast(unsigned, h);
}
__device__ __forceinline__ unsigned pkrtz_u32(float a, float b) {
    return __builtin_bit_cast(unsigned, __builtin_amdgcn_cvt_pkrtz(a, b));
}

// fp32[8] -> f16 hi/lo fragments via packed converter (hi rounding compensated by lo)
__device__ __forceinline__ void split8(const float* p, f16x8& hi, f16x8& lo) {
    unsigned hw[4], lw[4];
#pragma unroll
    for (int j = 0; j < 4; ++j) {
        float h0, h1;
        hw[j] = pkrtz_u32(p[2 * j], p[2 * j + 1], h0, h1);
        lw[j] = pkrtz_u32(p[2 * j] - h0, p[2 * j + 1] - h1);
    }
    hi = __builtin_bit_cast(f16x8, (u32x4){hw[0], hw[1], hw[2], hw[3]});
    lo = __builtin_bit_cast(f16x8, (u32x4){lw[0], lw[1], lw[2], lw[3]});
}

#define MF(A, B, C) __builtin_amdgcn_mfma_f32_16x16x32_f16((A), (B), (C), 0, 0, 0)

// =================== Phase 1 (MFMA, fp32-exact A-products) ===================
__global__ __launch_bounds__(256) void phase1m_kernel(const float* __restrict__ qkv,
                                                      float* __restrict__ ws) {
    const int chunk = blockIdx.x;
    const int bh = blockIdx.y;
    const int t = threadIdx.x;
    const int w = t >> 6, l = t & 63, g = l >> 4, c16 = l & 15;

    __shared__ float skT[32 * TSF2];       // 16.5 KB
    __shared__ _Float16 svhiT[32 * TSH2];  // 8.5 KB
    __shared__ _Float16 svloT[32 * TSH2];  // 8.5 KB

    const float4* kg4 = (const float4*)(qkv + (size_t)(NBH + bh) * (NTOK * DIM)) + (size_t)chunk * 256 * 8;
    const float4* vg4 = (const float4*)(qkv + (size_t)(2 * NBH + bh) * (NTOK * DIM)) + (size_t)chunk * 256 * 8;

    f32x4 acc[4][2][2];
    f32x4 accS[2][2];
#pragma unroll
    for (int i = 0; i < 4; ++i)
#pragma unroll
        for (int m = 0; m < 2; ++m)
#pragma unroll
            for (int fh = 0; fh < 2; ++fh) acc[i][m][fh] = (f32x4){0.f, 0.f, 0.f, 0.f};
#pragma unroll
    for (int m = 0; m < 2; ++m)
#pragma unroll
        for (int fh = 0; fh < 2; ++fh) accS[m][fh] = (f32x4){0.f, 0.f, 0.f, 0.f};

    const f16x8 ones = {(_Float16)1.f, (_Float16)1.f, (_Float16)1.f, (_Float16)1.f,
                        (_Float16)1.f, (_Float16)1.f, (_Float16)1.f, (_Float16)1.f};

    const int fq = t >> 5;     // 0..7 feature-quad
    const int tq = t & 31;     // 0..31 token-quad (within 128-tok half)

#pragma unroll 1
    for (int half = 0; half < 2; ++half) {
        __syncthreads();
        {   // ---- stage 128 tokens: 4x4 register-tile transpose ----
            const int nb = half * 128;
            float4 kf[4], vf[4];
#pragma unroll
            for (int c = 0; c < 4; ++c) {
                kf[c] = kg4[(size_t)(nb + tq * 4 + c) * 8 + fq];
                vf[c] = vg4[(size_t)(nb + tq * 4 + c) * 8 + fq];
            }
            const float kr[4][4] = {{kf[0].x, kf[1].x, kf[2].x, kf[3].x},
                                    {kf[0].y, kf[1].y, kf[2].y, kf[3].y},
                                    {kf[0].z, kf[1].z, kf[2].z, kf[3].z},
                                    {kf[0].w, kf[1].w, kf[2].w, kf[3].w}};
            const float vr[4][4] = {{vf[0].x, vf[1].x, vf[2].x, vf[3].x},
                                    {vf[0].y, vf[1].y, vf[2].y, vf[3].y},
                                    {vf[0].z, vf[1].z, vf[2].z, vf[3].z},
                                    {vf[0].w, vf[1].w, vf[2].w, vf[3].w}};
#pragma unroll
            for (int r = 0; r < 4; ++r) {
                *(float4*)(skT + (fq * 4 + r) * TSF2 + tq * 4) =
                    (float4){kr[r][0], kr[r][1], kr[r][2], kr[r][3]};
                float h0, h1, h2, h3;
                const unsigned hw0 = pkrtz_u32(vr[r][0], vr[r][1], h0, h1);
                const unsigned hw1 = pkrtz_u32(vr[r][2], vr[r][3], h2, h3);
                const unsigned lw0 = pkrtz_u32(vr[r][0] - h0, vr[r][1] - h1);
                const unsigned lw1 = pkrtz_u32(vr[r][2] - h2, vr[r][3] - h3);
                *(u32x2*)(svhiT + (fq * 4 + r) * TSH2 + tq * 4) = (u32x2){hw0, hw1};
                *(u32x2*)(svloT + (fq * 4 + r) * TSH2 + tq * 4) = (u32x2){lw0, lw1};
            }
        }
        __syncthreads();

#pragma unroll 1
        for (int it = 0; it < 4; ++it) {
            const int sl = it * 32 + 8 * g;
            float a0[8], a1[8];
            *(float4*)&a0[0] = *(const float4*)(skT + c16 * TSF2 + sl);
            *(float4*)&a0[4] = *(const float4*)(skT + c16 * TSF2 + sl + 4);
            *(float4*)&a1[0] = *(const float4*)(skT + (16 + c16) * TSF2 + sl);
            *(float4*)&a1[4] = *(const float4*)(skT + (16 + c16) * TSF2 + sl + 4);
            const f16x8 Bh0 = *(const f16x8*)(svhiT + c16 * TSH2 + sl);
            const f16x8 Bh1 = *(const f16x8*)(svhiT + (16 + c16) * TSH2 + sl);
            const f16x8 Bl0 = *(const f16x8*)(svloT + c16 * TSH2 + sl);
            const f16x8 Bl1 = *(const f16x8*)(svloT + (16 + c16) * TSH2 + sl);

#pragma unroll
            for (int i = 0; i < 4; ++i) {
                const int o = w + 4 * i;
                const int r0 = ((c16 + o) & 31) * TSF2;
                const int r1 = ((16 + c16 + o) & 31) * TSF2;
                float e0[8], e1[8], p0[8], p1[8];
                *(float4*)&e0[0] = *(const float4*)(skT + r0 + sl);
                *(float4*)&e0[4] = *(const float4*)(skT + r0 + sl + 4);
                *(float4*)&e1[0] = *(const float4*)(skT + r1 + sl);
                *(float4*)&e1[4] = *(const float4*)(skT + r1 + sl + 4);
#pragma unroll
                for (int j = 0; j < 8; ++j) { p0[j] = a0[j] * e0[j]; p1[j] = a1[j] * e1[j]; }
                f16x8 A0h, A0l, A1h, A1l;
                split8(p0, A0h, A0l);
                split8(p1, A1h, A1l);
                acc[i][0][0] = MF(A0h, Bh0, acc[i][0][0]);
                acc[i][0][0] = MF(A0l, Bh0, acc[i][0][0]);
                acc[i][0][0] = MF(A0h, Bl0, acc[i][0][0]);
                acc[i][0][1] = MF(A0h, Bh1, acc[i][0][1]);
                acc[i][0][1] = MF(A0l, Bh1, acc[i][0][1]);
                acc[i][0][1] = MF(A0h, Bl1, acc[i][0][1]);
                acc[i][1][0] = MF(A1h, Bh0, acc[i][1][0]);
                acc[i][1][0] = MF(A1l, Bh0, acc[i][1][0]);
                acc[i][1][0] = MF(A1h, Bl0, acc[i][1][0]);
                acc[i][1][1] = MF(A1h, Bh1, acc[i][1][1]);
                acc[i][1][1] = MF(A1l, Bh1, acc[i][1][1]);
                acc[i][1][1] = MF(A1h, Bl1, acc[i][1][1]);
            }

            if (w == 0) {            // o=16 (duplicate-symmetric pair rows)
                float p[8];
#pragma unroll
                for (int j = 0; j < 8; ++j) p[j] = a0[j] * a1[j];
                f16x8 Ah, Al;
                split8(p, Ah, Al);
                accS[0][0] = MF(Ah, Bh0, accS[0][0]);
                accS[0][0] = MF(Al, Bh0, accS[0][0]);
                accS[0][0] = MF(Ah, Bl0, accS[0][0]);
                accS[0][1] = MF(Ah, Bh1, accS[0][1]);
                accS[0][1] = MF(Al, Bh1, accS[0][1]);
                accS[0][1] = MF(Ah, Bl1, accS[0][1]);
            } else if (w == 1) {     // kv1: A = k (split)
                f16x8 K0h, K0l, K1h, K1l;
                split8(a0, K0h, K0l);
                split8(a1, K1h, K1l);
                accS[0][0] = MF(K0h, Bh0, accS[0][0]);
                accS[0][0] = MF(K0l, Bh0, accS[0][0]);
                accS[0][0] = MF(K0h, Bl0, accS[0][0]);
                accS[0][1] = MF(K0h, Bh1, accS[0][1]);
                accS[0][1] = MF(K0l, Bh1, accS[0][1]);
                accS[0][1] = MF(K0h, Bl1, accS[0][1]);
                accS[1][0] = MF(K1h, Bh0, accS[1][0]);
                accS[1][0] = MF(K1l, Bh0, accS[1][0]);
                accS[1][0] = MF(K1h, Bl0, accS[1][0]);
                accS[1][1] = MF(K1h, Bh1, accS[1][1]);
                accS[1][1] = MF(K1l, Bh1, accS[1][1]);
                accS[1][1] = MF(K1h, Bl1, accS[1][1]);
            } else if (w == 2) {     // ksum: A = ones, B = k (split)
                f16x8 K0h, K0l, K1h, K1l;
                split8(a0, K0h, K0l);
                split8(a1, K1h, K1l);
                accS[0][0] = MF(ones, K0h, accS[0][0]);
                accS[0][0] = MF(ones, K0l, accS[0][0]);
                accS[1][0] = MF(ones, K1h, accS[1][0]);
                accS[1][0] = MF(ones, K1l, accS[1][0]);
            } else {                 // vsum: A = ones, B = v hi/lo
                accS[0][0] = MF(ones, Bh0, accS[0][0]);
                accS[0][0] = MF(ones, Bl0, accS[0][0]);
                accS[0][1] = MF(ones, Bh1, accS[0][1]);
                accS[0][1] = MF(ones, Bl1, accS[0][1]);
            }
        }
    }

    // ---- store partials (f16, 2B) to slot `chunk`; sums fp32 to PSUM ----
    unsigned short* pb = (unsigned short*)(ws + PRT_OFF) + (size_t)SLOT1 * chunk + (size_t)bh * BHF1;
#pragma unroll
    for (int i = 0; i < 4; ++i) {
        const int o = w + 4 * i;
#pragma unroll
        for (int m = 0; m < 2; ++m)
#pragma unroll
            for (int fh = 0; fh < 2; ++fh)
#pragma unroll
                for (int r = 0; r < 4; ++r) {
                    const int R = o * 32 + 16 * m + 4 * g + r;
                    pb[(size_t)R * 32 + fh * 16 + c16] = h16(acc[i][m][fh][r]);
                }
    }
    if (w == 0) {
#pragma unroll
        for (int fh = 0; fh < 2; ++fh)
#pragma unroll
            for (int r = 0; r < 4; ++r) {
                const int R = 512 + 4 * g + r;
                const unsigned short hv = h16(accS[0][fh][r]);
                pb[(size_t)R * 32 + fh * 16 + c16] = hv;
                pb[(size_t)(R + 16) * 32 + fh * 16 + c16] = hv;
            }
    } else if (w == 1) {
#pragma unroll
        for (int m = 0; m < 2; ++m)
#pragma unroll
            for (int fh = 0; fh < 2; ++fh)
#pragma unroll
                for (int r = 0; r < 4; ++r) {
                    const int R = 544 + 16 * m + 4 * g + r;
                    pb[(size_t)R * 32 + fh * 16 + c16] = h16(accS[m][fh][r]);
                }
    } else if (w == 2) {
        if (g == 0) {
            float* ps = ws + PSUM_OFF + (size_t)chunk * (NBH * 64) + bh * 64;
            ps[c16] = accS[0][0][0];
            ps[16 + c16] = accS[1][0][0];
        }
    } else {
        if (g == 0) {
            float* ps = ws + PSUM_OFF + (size_t)chunk * (NBH * 64) + bh * 64;
            ps[32 + c16] = accS[0][0][0];
            ps[48 + c16] = accS[0][1][0];
        }
    }
}

// ============ reduce (16 f16 slots) + prep (f16 hi/lo frag pack) + sums ============
__global__ __launch_bounds__(256) void reduceprep_kernel(const float* __restrict__ ws,
                                                         float* __restrict__ wsw,
                                                         unsigned* __restrict__ bpk) {
    const int tid = blockIdx.x * 256 + threadIdx.x;
    if (tid < PK_HALF) {
        const int r = tid & 3;
        const int l = (tid >> 2) & 63;
        const int fh = (tid >> 8) & 1;
        const int kcbh = tid >> 9;
        const int kc = kcbh % KCH;
        const int bh = kcbh / KCH;
        const int f = fh * 16 + (l & 15);
        const int k0 = kc * 32 + ((l >> 4) << 3) + 2 * r;
        const float scale = (kc == 0 || kc == 16) ? 0.5f : 1.0f;
        float va = 0.f, vb = 0.f;
        const unsigned short* up = (const unsigned short*)(ws + PRT_OFF) +
                                   (size_t)bh * BHF1 + (size_t)k0 * 32 + f;
#pragma unroll
        for (int c = 0; c < KCH1; ++c) {
            va += h2f(up[(size_t)SLOT1 * c]);
            vb += h2f(up[(size_t)SLOT1 * c + 32]);
        }
        va *= scale; vb *= scale;
        float ha, hb;
        const unsigned hw = pkrtz_u32(va, vb, ha, hb);
        const unsigned lw = pkrtz_u32(va - ha, vb - hb);
        const int widx = ((bh * KCH + kc) * 2 + fh) * 512 + l * 4 + r;
        bpk[widx] = hw;
        bpk[widx + 256] = lw;
    } else {
        const int tid2 = tid - PK_HALF;
        if (tid2 < NBH * 64) {
            const int bh = tid2 >> 6;
            const int j = tid2 & 63;
            float s = 0.f;
            const float* src = ws + PSUM_OFF + bh * 64 + j;
#pragma unroll
            for (int c = 0; c < KCH1; ++c) s += src[(size_t)c * (NBH * 64)];
            wsw[(size_t)bh * BHF1 + SUMOFF1 + j] = s;
        }
    }
}

// ====== phase 2 (champion): y = Phi(A) * W(B) via f16 MFMA + pkrtz pack ======
#define EMIT_MFMA(PHIEXPR, KCEXPR) do { \
    unsigned hh[16]; \
    _Pragma("unroll") \
    for (int kp = 0; kp < 16; ++kp) { \
        const int j0 = 2 * kp, j1 = 2 * kp + 1; \
        const float p0 = (PHIEXPR(j0)); \
        const float p1 = (PHIEXPR(j1)); \
        hh[kp] = pkrtz_u32(p0, p1); \
    } \
    _Pragma("unroll") \
    for (int c4 = 0; c4 < 4; ++c4) { \
        u32x4 vh = {hh[4 * c4], hh[4 * c4 + 1], hh[4 * c4 + 2], hh[4 * c4 + 3]}; \
        *(u32x4*)&sph[t * 20 + c4 * 4] = vh; \
    } \
    const unsigned* bc = bbase + (size_t)(KCEXPR) * 1024; \
    const f16x8 Bh0 = __builtin_bit_cast(f16x8, *(const u32x4*)(bc + 0   + t * 4)); \
    const f16x8 Bl0 = __builtin_bit_cast(f16x8, *(const u32x4*)(bc + 256 + t * 4)); \
    const f16x8 Bh1 = __builtin_bit_cast(f16x8, *(const u32x4*)(bc + 512 + t * 4)); \
    const f16x8 Bl1 = __builtin_bit_cast(f16x8, *(const u32x4*)(bc + 768 + t * 4)); \
    _Pragma("unroll") \
    for (int T = 0; T < 4; ++T) { \
        const int ro = (T * 16 + arow) * 20 + acol; \
        const f16x8 Ah = __builtin_bit_cast(f16x8, *(const u32x4*)&sph[ro]); \
        acc[T][0] = MF(Ah, Bh0, acc[T][0]); \
        acc[T][0] = MF(Ah, Bl0, acc[T][0]); \
        acc[T][1] = MF(Ah, Bh1, acc[T][1]); \
        acc[T][1] = MF(Ah, Bl1, acc[T][1]); \
    } \
} while (0)

__global__ __launch_bounds__(P2TOK) void phase2m_kernel(const float* __restrict__ qkv,
                                                        const float* __restrict__ ws,
                                                        const unsigned* __restrict__ bpk,
                                                        float* __restrict__ out) {
    const int bh = blockIdx.y;
    const int tok0 = blockIdx.x * P2TOK;
    const int t = threadIdx.x;          // 0..63 == lane
    const int arow = t & 15;
    const int acol = (t >> 4) << 2;

    __shared__ unsigned sph[P2TOK * 20];
    __shared__ float sinv[P2TOK];

    float q[32];
    {
        const float4* q4 = (const float4*)(qkv + ((size_t)bh * NTOK + tok0 + t) * DIM);
#pragma unroll
        for (int i = 0; i < 8; ++i) {
            const float4 v = q4[i];
            q[4 * i + 0] = v.x; q[4 * i + 1] = v.y; q[4 * i + 2] = v.z; q[4 * i + 3] = v.w;
        }
    }
    {
        const float* ks = ws + (size_t)bh * BHF1 + SUMOFF1;
        float qk = 0.f;
#pragma unroll
        for (int d = 0; d < 32; ++d) qk += q[d] * ks[d];
        sinv[t] = 1.0f / (0.5f * qk * qk + qk + 1.0f);
    }

    f32x4 acc[4][2];
#pragma unroll
    for (int T = 0; T < 4; ++T)
#pragma unroll
        for (int fh = 0; fh < 2; ++fh) acc[T][fh] = (f32x4){0.f, 0.f, 0.f, 0.f};

    const unsigned* bbase = bpk + (size_t)bh * (KCH * 1024);

    float qr[32];
#pragma unroll
    for (int j = 0; j < 32; ++j) qr[j] = q[j];

#pragma unroll 1
    for (int kc4 = 0; kc4 < 16; kc4 += 4) {
#define PHI_S0(J) (q[(J)] * qr[(J)])
#define PHI_S1(J) (q[(J)] * qr[((J) + 1) & 31])
#define PHI_S2(J) (q[(J)] * qr[((J) + 2) & 31])
#define PHI_S3(J) (q[(J)] * qr[((J) + 3) & 31])
        EMIT_MFMA(PHI_S0, kc4 + 0);
        EMIT_MFMA(PHI_S1, kc4 + 1);
        EMIT_MFMA(PHI_S2, kc4 + 2);
        EMIT_MFMA(PHI_S3, kc4 + 3);
#undef PHI_S0
#undef PHI_S1
#undef PHI_S2
#undef PHI_S3
        // rotate qr by 4
        const float t0 = qr[0], t1 = qr[1], t2 = qr[2], t3 = qr[3];
#pragma unroll
        for (int j = 0; j < 28; ++j) qr[j] = qr[j + 4];
        qr[28] = t0; qr[29] = t1; qr[30] = t2; qr[31] = t3;
    }
    // kc = 16: qr is now q rotated by 16
    {
#define PHI_16(J) (q[(J)] * qr[(J)])
        EMIT_MFMA(PHI_16, 16);
#undef PHI_16
    }
    // kc = 17: kv1, phi = q
    {
#define PHI_Q(J) (q[(J)])
        EMIT_MFMA(PHI_Q, 17);
#undef PHI_Q
    }

    const float* vs = ws + (size_t)bh * BHF1 + SUMOFF1 + 32;
    const float vs0 = vs[t & 15];
    const float vs1 = vs[16 + (t & 15)];
#pragma unroll
    for (int T = 0; T < 4; ++T) {
#pragma unroll
        for (int r = 0; r < 4; ++r) {
            const int row = T * 16 + ((t >> 4) << 2) + r;
            const float iv = sinv[row];
            float* op = out + ((size_t)bh * NTOK + tok0 + row) * DIM + (t & 15);
            op[0]  = (acc[T][0][r] + vs0) * iv;
            op[16] = (acc[T][1][r] + vs1) * iv;
        }
    }
}

// =================== OLD fallback path (proven) ===================
__global__ __launch_bounds__(P1T) void phase1_kernel(const float* __restrict__ qkv,
                                                     float* __restrict__ ws, int direct) {
    const int chunk = blockIdx.x;
    const int bh = blockIdx.y;
    const int CHt = NTOK / gridDim.x;
    const int t = threadIdx.x;
    const float* kptr = qkv + (size_t)(NBH + bh) * (NTOK * DIM);
    const float* vptr = qkv + (size_t)(2 * NBH + bh) * (NTOK * DIM);
    float* base = ws + (direct ? (size_t)0 : (size_t)SLOT * (1 + chunk)) + (size_t)bh * BHF;

    __shared__ __align__(16) float sk[TILE][LSTR];
    __shared__ __align__(16) float sv[TILE][LSTR];

    int ia0, ib0, ia1, ib1;
    row_operands(t, ia0, ib0);
    row_operands(t + P1T, ia1, ib1);
    const float* a0 = &sk[0][ia0];
    const float* b0 = &sk[0][ib0];
    const float* a1 = &sk[0][ia1];
    const float* b1 = &sk[0][ib1];
    const float* sums = (t >= 288) ? &sv[0][t - 288] : ((t >= 256) ? &sk[0][t - 256] : &sk[0][0]);

    float acc0[32], acc1[32];
#pragma unroll
    for (int f = 0; f < 32; ++f) { acc0[f] = 0.f; acc1[f] = 0.f; }
    float accs = 0.f;

    if (t < 64) sk[t][32] = 1.0f;
    else if (t < 128) sk[t - 64][34] = 0.0f;

    const int n0 = chunk * CHt;
    for (int nt = 0; nt < CHt; nt += TILE) {
        __syncthreads();
        if (t < 256) {
            const float4* kg4 = (const float4*)(kptr + (size_t)(n0 + nt) * DIM);
            const float4* vg4 = (const float4*)(vptr + (size_t)(n0 + nt) * DIM);
            const int i0 = t, i1 = t + 256;
            *(float4*)&sk[i0 >> 3][(i0 & 7) << 2] = kg4[i0];
            *(float4*)&sk[i1 >> 3][(i1 & 7) << 2] = kg4[i1];
            *(float4*)&sv[i0 >> 3][(i0 & 7) << 2] = vg4[i0];
            *(float4*)&sv[i1 >> 3][(i1 & 7) << 2] = vg4[i1];
        }
        __syncthreads();
#pragma unroll 2
        for (int nn = 0; nn < TILE; ++nn) {
            const float s0 = a0[nn * LSTR] * b0[nn * LSTR];
            const float s1 = a1[nn * LSTR] * b1[nn * LSTR];
            const float* vrow = vptr + (size_t)(n0 + nt + nn) * DIM;
            float4 w[8];
#pragma unroll
            for (int j = 0; j < 8; ++j) w[j] = ((const float4*)vrow)[j];
#pragma unroll
            for (int j = 0; j < 8; ++j) {
                acc0[4 * j + 0] += s0 * w[j].x; acc0[4 * j + 1] += s0 * w[j].y;
                acc0[4 * j + 2] += s0 * w[j].z; acc0[4 * j + 3] += s0 * w[j].w;
                acc1[4 * j + 0] += s1 * w[j].x; acc1[4 * j + 1] += s1 * w[j].y;
                acc1[4 * j + 2] += s1 * w[j].z; acc1[4 * j + 3] += s1 * w[j].w;
            }
            if (t >= 256) accs += sums[nn * LSTR];
        }
    }

    {
        float* dst = base + (size_t)t * 32;
#pragma unroll
        for (int j = 0; j < 8; ++j) {
            float4 v; v.x = acc0[4 * j]; v.y = acc0[4 * j + 1];
            v.z = acc0[4 * j + 2]; v.w = acc0[4 * j + 3];
            ((float4*)dst)[j] = v;
        }
    }
    if (t < 240) {
        float* dst = base + (size_t)(t + P1T) * 32;
#pragma unroll
        for (int j = 0; j < 8; ++j) {
            float4 v; v.x = acc1[4 * j]; v.y = acc1[4 * j + 1];
            v.z = acc1[4 * j + 2]; v.w = acc1[4 * j + 3];
            ((float4*)dst)[j] = v;
        }
    }
    if (t >= 256) base[NROWS * 32 + (t - 256)] = accs;
}

__global__ __launch_bounds__(256) void phase2_kernel(const float* __restrict__ qkv,
                                                     const float* __restrict__ ws,
                                                     float* __restrict__ out) {
    const int bh = blockIdx.y;
    const int f0 = blockIdx.z << 4;
    const int t = threadIdx.x;
    const int tok0 = blockIdx.x * 256;
    const float* qptr = qkv + (size_t)bh * (NTOK * DIM) + (size_t)tok0 * DIM;
    const float* base = ws + (size_t)bh * BHF;
    const float* ksum = base + NROWS * 32;
    const float* vsum = ksum + 32;

    __shared__ float qT[32][256];
    {
        const float4* q4 = (const float4*)qptr + (size_t)t * 8;
#pragma unroll
        for (int i = 0; i < 8; ++i) {
            const float4 v = q4[i];
            qT[4 * i + 0][t] = v.x; qT[4 * i + 1][t] = v.y;
            qT[4 * i + 2][t] = v.z; qT[4 * i + 3][t] = v.w;
        }
    }
    __syncthreads();

    float y[16];
#pragma unroll
    for (int j = 0; j < 4; ++j) {
        const float4 v = *(const float4*)(vsum + f0 + 4 * j);
        y[4 * j + 0] = v.x; y[4 * j + 1] = v.y; y[4 * j + 2] = v.z; y[4 * j + 3] = v.w;
    }
    float qk = 0.f;
    const float* rowp = base + f0;
#pragma unroll 1
    for (int d = 0; d < 32; ++d) {
        const float qd = qT[d][t];
        qk += qd * ksum[d];
        {
            const float s = 0.5f * qd * qd;
            const float4* r = (const float4*)rowp;
#pragma unroll
            for (int j = 0; j < 4; ++j) {
                const float4 w = r[j];
                y[4 * j + 0] += s * w.x; y[4 * j + 1] += s * w.y;
                y[4 * j + 2] += s * w.z; y[4 * j + 3] += s * w.w;
            }
            rowp += 32;
        }
#pragma unroll 4
        for (int e = d + 1; e < 32; ++e) {
            const float s = qd * qT[e][t];
            const float4* r = (const float4*)rowp;
#pragma unroll
            for (int j = 0; j < 4; ++j) {
                const float4 w = r[j];
                y[4 * j + 0] += s * w.x; y[4 * j + 1] += s * w.y;
                y[4 * j + 2] += s * w.z; y[4 * j + 3] += s * w.w;
            }
            rowp += 32;
        }
    }
#pragma unroll 4
    for (int d = 0; d < 32; ++d) {
        const float qd = qT[d][t];
        const float4* r = (const float4*)rowp;
#pragma unroll
        for (int j = 0; j < 4; ++j) {
            const float4 w = r[j];
            y[4 * j + 0] += qd * w.x; y[4 * j + 1] += qd * w.y;
            y[4 * j + 2] += qd * w.z; y[4 * j + 3] += qd * w.w;
        }
        rowp += 32;
    }
    const float inv = 1.0f / (0.5f * qk * qk + qk + 1.0f);
    float4* o4 = (float4*)(out + (size_t)bh * (NTOK * DIM) + (size_t)(tok0 + t) * DIM + f0);
#pragma unroll
    for (int j = 0; j < 4; ++j) {
        float4 v;
        v.x = y[4 * j + 0] * inv; v.y = y[4 * j + 1] * inv;
        v.z = y[4 * j + 2] * inv; v.w = y[4 * j + 3] * inv;
        o4[j] = v;
    }
}

extern "C" void kernel_launch(void* const* d_in, const int* in_sizes, int n_in,
                              void* d_out, int out_size, void* d_ws, size_t ws_size,
                              hipStream_t stream) {
    const float* qkv = (const float*)d_in[0];
    float* out = (float*)d_out;
    float* ws = (float*)d_ws;

    const size_t need = ((size_t)BPK_OFF + PK_U32) * 4;
    if (ws_size >= need) {
        unsigned* bpk = (unsigned*)(ws + BPK_OFF);
        phase1m_kernel<<<dim3(KCH1, NBH), dim3(256), 0, stream>>>(qkv, ws);
        reduceprep_kernel<<<dim3((PK_HALF + NBH * 64) / 256), dim3(256), 0, stream>>>(ws, ws, bpk);
        phase2m_kernel<<<dim3(NTOK / P2TOK, NBH), dim3(P2TOK), 0, stream>>>(qkv, ws, bpk, out);
    } else {
        phase1_kernel<<<dim3(1, NBH), dim3(P1T), 0, stream>>>(qkv, ws, 1);
        phase2_kernel<<<dim3(NTOK / 256, NBH, 2), dim3(256), 0, stream>>>(qkv, ws, out);
    }
}